// Round 4
// baseline (231.506 us; speedup 1.0000x reference)
//
#include <hip/hip_runtime.h>
#include <hip/hip_bf16.h>

#define BB 2
#define TT 2048
#define CC 1024
#define NHEAD 16
#define DHEAD 64
#define MM (BB*TT)
#define KVB 128

using bf16 = __hip_bfloat16;
typedef __bf16 bf16x8 __attribute__((ext_vector_type(8)));
typedef __bf16 bf16x4 __attribute__((ext_vector_type(4)));
typedef float f32x4 __attribute__((ext_vector_type(4)));

static __device__ __forceinline__ bf16 f2b(float f) { return __float2bfloat16(f); }
static __device__ __forceinline__ float fast_exp2(float f) { return __builtin_amdgcn_exp2f(f); }

// async global -> LDS, 16B per lane (dest must be wave-uniform base + lane*16)
static __device__ __forceinline__ void gload16(const bf16* g, bf16* l) {
  __builtin_amdgcn_global_load_lds((__attribute__((address_space(1))) const void*)g,
                                   (__attribute__((address_space(3))) void*)l, 16, 0, 0);
}

// ---------------- fp32 -> bf16 linear convert (vectorized) ----------------
__global__ void k_convert(const float* __restrict__ in, bf16* __restrict__ out, int n4) {
  int i = blockIdx.x * blockDim.x + threadIdx.x;
  if (i >= n4) return;
  float4 v = reinterpret_cast<const float4*>(in)[i];
  bf16 o[4] = { f2b(v.x), f2b(v.y), f2b(v.z), f2b(v.w) };
  reinterpret_cast<uint2*>(out)[i] = *reinterpret_cast<uint2*>(o);
}

// ------------- fp32 (R x Cc) -> bf16 transposed (Cc x R) -------------
__global__ void k_transpose(const float* __restrict__ W, bf16* __restrict__ WT, int R, int Cc) {
  __shared__ float tile[32][33];
  int c0 = blockIdx.x * 32, r0 = blockIdx.y * 32;
  int tx = threadIdx.x, ty = threadIdx.y;   // 32 x 8
#pragma unroll
  for (int i = 0; i < 4; ++i)
    tile[ty + 8*i][tx] = W[(size_t)(r0 + ty + 8*i) * Cc + c0 + tx];
  __syncthreads();
#pragma unroll
  for (int i = 0; i < 4; ++i)
    WT[(size_t)(c0 + ty + 8*i) * R + r0 + tx] = f2b(tile[tx][ty + 8*i]);
}

// ------------- per-head V (T x D) -> V^T (D x T), bf16 -------------
__global__ void k_vtrans(const bf16* __restrict__ V, bf16* __restrict__ VT) {
  __shared__ bf16 tile[32][33];
  const int bn = blockIdx.z;
  const int d0 = blockIdx.x * 32, t0 = blockIdx.y * 32;
  const size_t base = (size_t)bn * TT * DHEAD;
  int tx = threadIdx.x, ty = threadIdx.y;   // 32 x 8
#pragma unroll
  for (int i = 0; i < 4; ++i)
    tile[ty + 8*i][tx] = V[base + (size_t)(t0 + ty + 8*i) * DHEAD + d0 + tx];
  __syncthreads();
#pragma unroll
  for (int i = 0; i < 4; ++i)
    VT[base + (size_t)(d0 + ty + 8*i) * TT + t0 + tx] = tile[tx][ty + 8*i];
}

// ---------------- 128x128 bf16 GEMM (m97 structure: global_load_lds, linear LDS) ----------------
// MODE 0: qkv epilogue (scatter to Q/K/V in (B,N,T,D); Q pre-scaled by log2e/sqrt(D))
// MODE 1: fp32 out + bias, row-major MxCC
template<int MODE>
__global__ __launch_bounds__(256)
void k_gemm(const bf16* __restrict__ A, const bf16* __restrict__ Bt,
            const float* __restrict__ bias, float* __restrict__ outF,
            bf16* __restrict__ Qb, bf16* __restrict__ Kb, bf16* __restrict__ Vb,
            int K)
{
  const int tid  = threadIdx.x;
  const int wave = tid >> 6, lane = tid & 63;
  const int l16 = lane & 15, l4 = lane >> 4;
  const int wr = wave >> 1, wc = wave & 1;
  const int m0 = blockIdx.y * 128, n0 = blockIdx.x * 128;

  __shared__ __align__(16) bf16 As[128*32];   // linear [row][32]
  __shared__ __align__(16) bf16 Bs[128*32];

  f32x4 acc[4][4];
#pragma unroll
  for (int m = 0; m < 4; ++m)
#pragma unroll
    for (int n = 0; n < 4; ++n) acc[m][n] = 0.f;

  const int sr = tid >> 2;            // 0..63
  const int sc = (tid & 3) * 8;       // 0,8,16,24

  for (int k0 = 0; k0 < K; k0 += 32) {
    __syncthreads();
#pragma unroll
    for (int i = 0; i < 2; ++i) {
      gload16(&A [(size_t)(m0 + i*64 + sr) * K + k0 + sc], &As[i*2048 + tid*8]);
      gload16(&Bt[(size_t)(n0 + i*64 + sr) * K + k0 + sc], &Bs[i*2048 + tid*8]);
    }
    __syncthreads();   // compiler emits vmcnt(0) drain here
    bf16x8 af[4], bfr[4];
#pragma unroll
    for (int m = 0; m < 4; ++m)
      af[m] = *reinterpret_cast<const bf16x8*>(&As[(wr*64 + m*16 + l16)*32 + l4*8]);
#pragma unroll
    for (int n = 0; n < 4; ++n)
      bfr[n] = *reinterpret_cast<const bf16x8*>(&Bs[(wc*64 + n*16 + l16)*32 + l4*8]);
#pragma unroll
    for (int m = 0; m < 4; ++m)
#pragma unroll
      for (int n = 0; n < 4; ++n)
        acc[m][n] = __builtin_amdgcn_mfma_f32_16x16x32_bf16(af[m], bfr[n], acc[m][n], 0, 0, 0);
  }

  if (MODE == 0) {
    const int which = n0 >> 10;
    bf16* __restrict__ dst = (which == 0) ? Qb : (which == 1) ? Kb : Vb;
    const float qsc = (which == 0) ? 0.125f * 1.4426950408889634f : 1.0f;
#pragma unroll
    for (int m = 0; m < 4; ++m)
#pragma unroll
      for (int n = 0; n < 4; ++n)
#pragma unroll
        for (int j = 0; j < 4; ++j) {
          int gr = m0 + wr*64 + m*16 + l4*4 + j;
          int gc = n0 + wc*64 + n*16 + l16;
          float val = (acc[m][n][j] + bias[gc]) * qsc;
          int c = gc & (CC-1), head = c >> 6, d = c & 63;
          int b = gr >> 11, t = gr & (TT-1);
          dst[(((size_t)b*NHEAD + head)*TT + t)*DHEAD + d] = f2b(val);
        }
  } else {
#pragma unroll
    for (int m = 0; m < 4; ++m)
#pragma unroll
      for (int n = 0; n < 4; ++n)
#pragma unroll
        for (int j = 0; j < 4; ++j) {
          int gr = m0 + wr*64 + m*16 + l4*4 + j;
          int gc = n0 + wc*64 + n*16 + l16;
          outF[(size_t)gr * CC + gc] = acc[m][n][j] + bias[gc];
        }
  }
}

// ---------------- flash attention v3 ----------------
// KVB=128; K staged in LDS with async reg-prefetch (T14); V read direct from L1/L2;
// swapped-QK in-register softmax, exp2 domain, defer-max (THR=8).
__global__ __launch_bounds__(256, 4)
void k_attn(const bf16* __restrict__ Qg, const bf16* __restrict__ Kg,
            const bf16* __restrict__ VTg, bf16* __restrict__ Aout)
{
  const int tid  = threadIdx.x;
  const int wave = tid >> 6, lane = tid & 63;
  const int l16 = lane & 15, l4 = lane >> 4;
  const int bn = blockIdx.y;
  const int b = bn >> 4, h = bn & (NHEAD-1);
  const int q0 = blockIdx.x * 64;

  __shared__ __align__(16) bf16 Ks[KVB][72];        // [kv][d], pitch 36 dwords: beat-conflict-free
  __shared__ __align__(16) bf16 Pl[4][16][KVB+8];   // per-wave P[q][kv], pitch 68 dwords

  const size_t hb = (size_t)bn * TT * DHEAD;
  const bf16* __restrict__ Kbase = Kg + hb;
  const bf16* __restrict__ Vbase = VTg + hb;

  // Q fragments (B-operand of swapped QK): lane l16 holds Q[q0+w*16+l16][kk*32+l4*8..+7]
  bf16x8 qf[2];
#pragma unroll
  for (int kk = 0; kk < 2; ++kk)
    qf[kk] = *reinterpret_cast<const bf16x8*>(
        &Qg[hb + (size_t)(q0 + wave*16 + l16) * DHEAD + kk*32 + l4*8]);

  f32x4 o[4];
#pragma unroll
  for (int n = 0; n < 4; ++n) o[n] = 0.f;
  float mrun = -1e30f, lrun = 0.f;   // per-lane stats for q = l16 (replicated across l4)

  // K staging geometry: thread covers row kr, cols kc..kc+31
  const int kr = tid >> 1;            // 0..127
  const int kc = (tid & 1) * 32;      // 0 / 32

  bf16x8 kreg[4];
#pragma unroll
  for (int i = 0; i < 4; ++i)
    kreg[i] = *reinterpret_cast<const bf16x8*>(&Kbase[(size_t)kr * DHEAD + kc + 8*i]);
#pragma unroll
  for (int i = 0; i < 4; ++i)
    *reinterpret_cast<bf16x8*>(&Ks[kr][kc + 8*i]) = kreg[i];

  for (int t0 = 0; t0 < TT; t0 += KVB) {
    __syncthreads();                      // K tile t0 visible
    const bool more = (t0 + KVB < TT);
    if (more) {                           // T14: issue next-tile loads, commit after compute
#pragma unroll
      for (int i = 0; i < 4; ++i)
        kreg[i] = *reinterpret_cast<const bf16x8*>(
            &Kbase[(size_t)(t0 + KVB + kr) * DHEAD + kc + 8*i]);
    }

    // S^T = K Q^T : lane holds S^T[kv = n*16 + l4*4 + j][q = l16], n = 0..7
    f32x4 s[8];
#pragma unroll
    for (int n = 0; n < 8; ++n) s[n] = 0.f;
    __builtin_amdgcn_s_setprio(1);
#pragma unroll
    for (int n = 0; n < 8; ++n) {
      bf16x8 kf0 = *reinterpret_cast<const bf16x8*>(&Ks[n*16 + l16][l4*8]);
      bf16x8 kf1 = *reinterpret_cast<const bf16x8*>(&Ks[n*16 + l16][32 + l4*8]);
      s[n] = __builtin_amdgcn_mfma_f32_16x16x32_bf16(kf0, qf[0], s[n], 0, 0, 0);
      s[n] = __builtin_amdgcn_mfma_f32_16x16x32_bf16(kf1, qf[1], s[n], 0, 0, 0);
    }
    __builtin_amdgcn_s_setprio(0);

    // --- online softmax (exp2 domain), defer-max THR=8 ---
    float pm = s[0][0];
#pragma unroll
    for (int n = 0; n < 8; ++n)
#pragma unroll
      for (int j = 0; j < 4; ++j) pm = fmaxf(pm, s[n][j]);
    pm = fmaxf(pm, __shfl_xor(pm, 16, 64));
    pm = fmaxf(pm, __shfl_xor(pm, 32, 64));

    if (!__all(pm <= mrun + 8.f)) {
      float mn = fmaxf(mrun, pm);
      float corr = fast_exp2(mrun - mn);
      mrun = mn;
      lrun *= corr;
      float cj[4];
#pragma unroll
      for (int j = 0; j < 4; ++j)
        cj[j] = __shfl(corr, ((lane >> 4) << 2) + j, 64);
#pragma unroll
      for (int n = 0; n < 4; ++n)
#pragma unroll
        for (int j = 0; j < 4; ++j) o[n][j] *= cj[j];
    }

    float psum = 0.f;
#pragma unroll
    for (int n = 0; n < 8; ++n) {
      bf16x4 pk;
#pragma unroll
      for (int j = 0; j < 4; ++j) {
        float pv = fast_exp2(s[n][j] - mrun);
        psum += pv;
        pk[j] = (__bf16)pv;
      }
      *reinterpret_cast<bf16x4*>(&Pl[wave][l16][n*16 + l4*4]) = pk;
    }
    psum += __shfl_xor(psum, 16, 64);
    psum += __shfl_xor(psum, 32, 64);
    lrun += psum;

    // O += P V : A = P[q][kv] (per-wave LDS), B = V^T[d][kv] direct from global (L1/L2)
    bf16x8 pf[4];
#pragma unroll
    for (int kk = 0; kk < 4; ++kk)
      pf[kk] = *reinterpret_cast<const bf16x8*>(&Pl[wave][l16][kk*32 + l4*8]);
    __builtin_amdgcn_s_setprio(1);
#pragma unroll
    for (int n = 0; n < 4; ++n) {
#pragma unroll
      for (int kk = 0; kk < 4; ++kk) {
        bf16x8 vf = *reinterpret_cast<const bf16x8*>(
            &Vbase[(size_t)(n*16 + l16) * TT + t0 + kk*32 + l4*8]);
        o[n] = __builtin_amdgcn_mfma_f32_16x16x32_bf16(pf[kk], vf, o[n], 0, 0, 0);
      }
    }
    __builtin_amdgcn_s_setprio(0);

    __syncthreads();                      // all waves done reading Ks
    if (more) {
#pragma unroll
      for (int i = 0; i < 4; ++i)
        *reinterpret_cast<bf16x8*>(&Ks[kr][kc + 8*i]) = kreg[i];
    }
  }

  // epilogue: broadcast 1/l from softmax lanes to O-row lanes, store (B,T,C)
  float linv = 1.0f / lrun;
  float lj[4];
#pragma unroll
  for (int j = 0; j < 4; ++j)
    lj[j] = __shfl(linv, ((lane >> 4) << 2) + j, 64);
#pragma unroll
  for (int j = 0; j < 4; ++j) {
    int gt = q0 + wave*16 + l4*4 + j;
#pragma unroll
    for (int n = 0; n < 4; ++n)
      Aout[((size_t)(b*TT + gt))*CC + h*DHEAD + n*16 + l16] = f2b(o[n][j] * lj[j]);
  }
}

extern "C" void kernel_launch(void* const* d_in, const int* in_sizes, int n_in,
                              void* d_out, int out_size, void* d_ws, size_t ws_size,
                              hipStream_t stream)
{
  const float* x     = (const float*)d_in[0];
  const float* Wqkv  = (const float*)d_in[1];
  const float* bqkv  = (const float*)d_in[2];
  const float* Wproj = (const float*)d_in[3];
  const float* bproj = (const float*)d_in[4];
  float* out = (float*)d_out;

  char* p = (char*)d_ws;
  bf16* Xb     = (bf16*)p;  p += (size_t)MM*CC*2;        // 8 MB (dead after QKV GEMM)
  bf16* WqkvT  = (bf16*)p;  p += (size_t)3*CC*CC*2;      // 6 MB
  bf16* WprojT = (bf16*)p;  p += (size_t)CC*CC*2;        // 2 MB
  bf16* Qb     = (bf16*)p;  p += (size_t)MM*CC*2;        // 8 MB (B,N,T,D)
  bf16* Kb     = (bf16*)p;  p += (size_t)MM*CC*2;        // 8 MB
  bf16* Vb     = (bf16*)p;  p += (size_t)MM*CC*2;        // 8 MB
  bf16* Attn   = (bf16*)p;  p += (size_t)MM*CC*2;        // 8 MB (B,T,C)
  bf16* VTb    = Xb;                                     // reuse Xb: (B,N,D,T)

  k_convert<<<(MM*CC/4 + 255)/256, 256, 0, stream>>>(x, Xb, MM*CC/4);
  k_transpose<<<dim3(3*CC/32, CC/32), dim3(32, 8), 0, stream>>>(Wqkv, WqkvT, CC, 3*CC);
  k_transpose<<<dim3(CC/32, CC/32), dim3(32, 8), 0, stream>>>(Wproj, WprojT, CC, CC);

  k_gemm<0><<<dim3(3*CC/128, MM/128), 256, 0, stream>>>(Xb, WqkvT, bqkv, nullptr, Qb, Kb, Vb, CC);
  k_vtrans<<<dim3(DHEAD/32, TT/32, BB*NHEAD), dim3(32, 8), 0, stream>>>(Vb, VTb);
  k_attn<<<dim3(TT/64, BB*NHEAD), 256, 0, stream>>>(Qb, Kb, VTb, Attn);
  k_gemm<1><<<dim3(CC/128, MM/128), 256, 0, stream>>>(Attn, WprojT, bproj, out, nullptr, nullptr, nullptr, CC);
}

// Round 5
// 177.689 us; speedup vs baseline: 1.3029x; 1.3029x over previous
//
#include <hip/hip_runtime.h>
#include <hip/hip_bf16.h>

#define BB 2
#define TT 2048
#define CC 1024
#define NHEAD 16
#define DHEAD 64
#define MM (BB*TT)
#define KVB 128

using bf16 = __hip_bfloat16;
typedef __bf16 bf16x8 __attribute__((ext_vector_type(8)));
typedef __bf16 bf16x4 __attribute__((ext_vector_type(4)));
typedef float f32x4 __attribute__((ext_vector_type(4)));

static __device__ __forceinline__ bf16 f2b(float f) { return __float2bfloat16(f); }
static __device__ __forceinline__ float fast_exp2(float f) { return __builtin_amdgcn_exp2f(f); }

// async global -> LDS, 16B per lane (dest must be wave-uniform base + lane*16)
static __device__ __forceinline__ void gload16(const bf16* g, bf16* l) {
  __builtin_amdgcn_global_load_lds((__attribute__((address_space(1))) const void*)g,
                                   (__attribute__((address_space(3))) void*)l, 16, 0, 0);
}

// ---------------- fp32 -> bf16 linear convert (vectorized) ----------------
__global__ void k_convert(const float* __restrict__ in, bf16* __restrict__ out, int n4) {
  int i = blockIdx.x * blockDim.x + threadIdx.x;
  if (i >= n4) return;
  float4 v = reinterpret_cast<const float4*>(in)[i];
  bf16 o[4] = { f2b(v.x), f2b(v.y), f2b(v.z), f2b(v.w) };
  reinterpret_cast<uint2*>(out)[i] = *reinterpret_cast<uint2*>(o);
}

// ------------- fp32 (R x Cc) -> bf16 transposed (Cc x R) -------------
__global__ void k_transpose(const float* __restrict__ W, bf16* __restrict__ WT, int R, int Cc) {
  __shared__ float tile[32][33];
  int c0 = blockIdx.x * 32, r0 = blockIdx.y * 32;
  int tx = threadIdx.x, ty = threadIdx.y;   // 32 x 8
#pragma unroll
  for (int i = 0; i < 4; ++i)
    tile[ty + 8*i][tx] = W[(size_t)(r0 + ty + 8*i) * Cc + c0 + tx];
  __syncthreads();
#pragma unroll
  for (int i = 0; i < 4; ++i)
    WT[(size_t)(c0 + ty + 8*i) * R + r0 + tx] = f2b(tile[tx][ty + 8*i]);
}

// ------------- per-head V (T x D) -> V^T (D x T), bf16 -------------
__global__ void k_vtrans(const bf16* __restrict__ V, bf16* __restrict__ VT) {
  __shared__ bf16 tile[32][33];
  const int bn = blockIdx.z;
  const int d0 = blockIdx.x * 32, t0 = blockIdx.y * 32;
  const size_t base = (size_t)bn * TT * DHEAD;
  int tx = threadIdx.x, ty = threadIdx.y;   // 32 x 8
#pragma unroll
  for (int i = 0; i < 4; ++i)
    tile[ty + 8*i][tx] = V[base + (size_t)(t0 + ty + 8*i) * DHEAD + d0 + tx];
  __syncthreads();
#pragma unroll
  for (int i = 0; i < 4; ++i)
    VT[base + (size_t)(d0 + ty + 8*i) * TT + t0 + tx] = tile[tx][ty + 8*i];
}

// ---------------- 128x128 bf16 GEMM (m97 structure: global_load_lds, linear LDS) ----------------
template<int MODE>
__global__ __launch_bounds__(256)
void k_gemm(const bf16* __restrict__ A, const bf16* __restrict__ Bt,
            const float* __restrict__ bias, float* __restrict__ outF,
            bf16* __restrict__ Qb, bf16* __restrict__ Kb, bf16* __restrict__ Vb,
            int K)
{
  const int tid  = threadIdx.x;
  const int wave = tid >> 6, lane = tid & 63;
  const int l16 = lane & 15, l4 = lane >> 4;
  const int wr = wave >> 1, wc = wave & 1;
  const int m0 = blockIdx.y * 128, n0 = blockIdx.x * 128;

  __shared__ __align__(16) bf16 As[128*32];   // linear [row][32]
  __shared__ __align__(16) bf16 Bs[128*32];

  f32x4 acc[4][4];
#pragma unroll
  for (int m = 0; m < 4; ++m)
#pragma unroll
    for (int n = 0; n < 4; ++n) acc[m][n] = 0.f;

  const int sr = tid >> 2;            // 0..63
  const int sc = (tid & 3) * 8;       // 0,8,16,24

  for (int k0 = 0; k0 < K; k0 += 32) {
    __syncthreads();
#pragma unroll
    for (int i = 0; i < 2; ++i) {
      gload16(&A [(size_t)(m0 + i*64 + sr) * K + k0 + sc], &As[i*2048 + tid*8]);
      gload16(&Bt[(size_t)(n0 + i*64 + sr) * K + k0 + sc], &Bs[i*2048 + tid*8]);
    }
    __syncthreads();
    bf16x8 af[4], bfr[4];
#pragma unroll
    for (int m = 0; m < 4; ++m)
      af[m] = *reinterpret_cast<const bf16x8*>(&As[(wr*64 + m*16 + l16)*32 + l4*8]);
#pragma unroll
    for (int n = 0; n < 4; ++n)
      bfr[n] = *reinterpret_cast<const bf16x8*>(&Bs[(wc*64 + n*16 + l16)*32 + l4*8]);
#pragma unroll
    for (int m = 0; m < 4; ++m)
#pragma unroll
      for (int n = 0; n < 4; ++n)
        acc[m][n] = __builtin_amdgcn_mfma_f32_16x16x32_bf16(af[m], bfr[n], acc[m][n], 0, 0, 0);
  }

  if (MODE == 0) {
    const int which = n0 >> 10;
    bf16* __restrict__ dst = (which == 0) ? Qb : (which == 1) ? Kb : Vb;
    const float qsc = (which == 0) ? 0.125f * 1.4426950408889634f : 1.0f;
#pragma unroll
    for (int m = 0; m < 4; ++m)
#pragma unroll
      for (int n = 0; n < 4; ++n)
#pragma unroll
        for (int j = 0; j < 4; ++j) {
          int gr = m0 + wr*64 + m*16 + l4*4 + j;
          int gc = n0 + wc*64 + n*16 + l16;
          float val = (acc[m][n][j] + bias[gc]) * qsc;
          int c = gc & (CC-1), head = c >> 6, d = c & 63;
          int b = gr >> 11, t = gr & (TT-1);
          dst[(((size_t)b*NHEAD + head)*TT + t)*DHEAD + d] = f2b(val);
        }
  } else {
#pragma unroll
    for (int m = 0; m < 4; ++m)
#pragma unroll
      for (int n = 0; n < 4; ++n)
#pragma unroll
        for (int j = 0; j < 4; ++j) {
          int gr = m0 + wr*64 + m*16 + l4*4 + j;
          int gc = n0 + wc*64 + n*16 + l16;
          outF[(size_t)gr * CC + gc] = acc[m][n][j] + bias[gc];
        }
  }
}

// ---------------- flash attention v4 ----------------
// KVB=128; K and V^T staged in LDS, T14 reg-prefetch (issue after top barrier,
// commit after bottom barrier); swapped-QK in-register softmax, exp2, defer-max.
// 1D grid 1024 = 8 XCDs x 128; each XCD owns 4 heads (K/V L2 locality).
__global__ __launch_bounds__(256, 4)
void k_attn(const bf16* __restrict__ Qg, const bf16* __restrict__ Kg,
            const bf16* __restrict__ VTg, bf16* __restrict__ Aout)
{
  const int tid  = threadIdx.x;
  const int wave = tid >> 6, lane = tid & 63;
  const int l16 = lane & 15, l4 = lane >> 4;

  // XCD-aware swizzle: flat = 0..1023; xcd = flat&7 gets heads xcd*4..xcd*4+3
  const int flat = blockIdx.x;
  const int xcd = flat & 7, i6 = flat >> 3;
  const int bn = xcd*4 + (i6 >> 5);          // 0..31 (b*16+h)
  const int q0 = (i6 & 31) * 64;
  const int b = bn >> 4, h = bn & (NHEAD-1);

  __shared__ __align__(16) bf16 Ks[KVB][72];        // [kv][d]
  __shared__ __align__(16) bf16 Vt[DHEAD][KVB+8];   // [d][kv]
  __shared__ __align__(16) bf16 Pl[4][16][KVB+8];   // per-wave P[q][kv]

  const size_t hb = (size_t)bn * TT * DHEAD;
  const bf16* __restrict__ Kbase = Kg + hb;
  const bf16* __restrict__ Vbase = VTg + hb;

  bf16x8 qf[2];
#pragma unroll
  for (int kk = 0; kk < 2; ++kk)
    qf[kk] = *reinterpret_cast<const bf16x8*>(
        &Qg[hb + (size_t)(q0 + wave*16 + l16) * DHEAD + kk*32 + l4*8]);

  f32x4 o[4];
#pragma unroll
  for (int n = 0; n < 4; ++n) o[n] = 0.f;
  float mrun = -1e30f, lrun = 0.f;

  // staging geometry
  const int kr = tid >> 1, kc = (tid & 1) * 32;   // K: 128 rows x 64
  const int vr = tid >> 2, vc = (tid & 3) * 32;   // V^T: 64 rows x 128

  bf16x8 kreg[4], vreg[4];
#pragma unroll
  for (int i = 0; i < 4; ++i) {
    kreg[i] = *reinterpret_cast<const bf16x8*>(&Kbase[(size_t)kr * DHEAD + kc + 8*i]);
    vreg[i] = *reinterpret_cast<const bf16x8*>(&Vbase[(size_t)vr * TT + vc + 8*i]);
  }
#pragma unroll
  for (int i = 0; i < 4; ++i) {
    *reinterpret_cast<bf16x8*>(&Ks[kr][kc + 8*i]) = kreg[i];
    *reinterpret_cast<bf16x8*>(&Vt[vr][vc + 8*i]) = vreg[i];
  }

  for (int t0 = 0; t0 < TT; t0 += KVB) {
    __syncthreads();                      // tile t0 visible in LDS
    const bool more = (t0 + KVB < TT);
    if (more) {                           // T14: issue next-tile loads now, commit later
#pragma unroll
      for (int i = 0; i < 4; ++i) {
        kreg[i] = *reinterpret_cast<const bf16x8*>(
            &Kbase[(size_t)(t0 + KVB + kr) * DHEAD + kc + 8*i]);
        vreg[i] = *reinterpret_cast<const bf16x8*>(
            &Vbase[(size_t)vr * TT + t0 + KVB + vc + 8*i]);
      }
    }

    // S^T = K Q^T : lane holds S^T[kv = n*16 + l4*4 + j][q = l16]
    f32x4 s[8];
#pragma unroll
    for (int n = 0; n < 8; ++n) s[n] = 0.f;
    __builtin_amdgcn_s_setprio(1);
#pragma unroll
    for (int n = 0; n < 8; ++n) {
      bf16x8 kf0 = *reinterpret_cast<const bf16x8*>(&Ks[n*16 + l16][l4*8]);
      bf16x8 kf1 = *reinterpret_cast<const bf16x8*>(&Ks[n*16 + l16][32 + l4*8]);
      s[n] = __builtin_amdgcn_mfma_f32_16x16x32_bf16(kf0, qf[0], s[n], 0, 0, 0);
      s[n] = __builtin_amdgcn_mfma_f32_16x16x32_bf16(kf1, qf[1], s[n], 0, 0, 0);
    }
    __builtin_amdgcn_s_setprio(0);

    // --- online softmax (exp2 domain), defer-max THR=8 ---
    float pm = s[0][0];
#pragma unroll
    for (int n = 0; n < 8; ++n)
#pragma unroll
      for (int j = 0; j < 4; ++j) pm = fmaxf(pm, s[n][j]);
    pm = fmaxf(pm, __shfl_xor(pm, 16, 64));
    pm = fmaxf(pm, __shfl_xor(pm, 32, 64));

    if (!__all(pm <= mrun + 8.f)) {
      float mn = fmaxf(mrun, pm);
      float corr = fast_exp2(mrun - mn);
      mrun = mn;
      lrun *= corr;
      float cj[4];
#pragma unroll
      for (int j = 0; j < 4; ++j)
        cj[j] = __shfl(corr, ((lane >> 4) << 2) + j, 64);
#pragma unroll
      for (int n = 0; n < 4; ++n)
#pragma unroll
        for (int j = 0; j < 4; ++j) o[n][j] *= cj[j];
    }

    float psum = 0.f;
#pragma unroll
    for (int n = 0; n < 8; ++n) {
      bf16x4 pk;
#pragma unroll
      for (int j = 0; j < 4; ++j) {
        float pv = fast_exp2(s[n][j] - mrun);
        psum += pv;
        pk[j] = (__bf16)pv;
      }
      *reinterpret_cast<bf16x4*>(&Pl[wave][l16][n*16 + l4*4]) = pk;
    }
    psum += __shfl_xor(psum, 16, 64);
    psum += __shfl_xor(psum, 32, 64);
    lrun += psum;

    // O += P V : A = P[q][kv] (per-wave LDS), B = V^T[d][kv] (LDS)
    bf16x8 pf[4];
#pragma unroll
    for (int kk = 0; kk < 4; ++kk)
      pf[kk] = *reinterpret_cast<const bf16x8*>(&Pl[wave][l16][kk*32 + l4*8]);
    __builtin_amdgcn_s_setprio(1);
#pragma unroll
    for (int n = 0; n < 4; ++n)
#pragma unroll
      for (int kk = 0; kk < 4; ++kk) {
        bf16x8 vf = *reinterpret_cast<const bf16x8*>(&Vt[n*16 + l16][kk*32 + l4*8]);
        o[n] = __builtin_amdgcn_mfma_f32_16x16x32_bf16(pf[kk], vf, o[n], 0, 0, 0);
      }
    __builtin_amdgcn_s_setprio(0);

    __syncthreads();                      // all waves done reading Ks/Vt
    if (more) {
#pragma unroll
      for (int i = 0; i < 4; ++i) {
        *reinterpret_cast<bf16x8*>(&Ks[kr][kc + 8*i]) = kreg[i];
        *reinterpret_cast<bf16x8*>(&Vt[vr][vc + 8*i]) = vreg[i];
      }
    }
  }

  // epilogue
  float linv = 1.0f / lrun;
  float lj[4];
#pragma unroll
  for (int j = 0; j < 4; ++j)
    lj[j] = __shfl(linv, ((lane >> 4) << 2) + j, 64);
#pragma unroll
  for (int j = 0; j < 4; ++j) {
    int gt = q0 + wave*16 + l4*4 + j;
#pragma unroll
    for (int n = 0; n < 4; ++n)
      Aout[((size_t)(b*TT + gt))*CC + h*DHEAD + n*16 + l16] = f2b(o[n][j] * lj[j]);
  }
}

extern "C" void kernel_launch(void* const* d_in, const int* in_sizes, int n_in,
                              void* d_out, int out_size, void* d_ws, size_t ws_size,
                              hipStream_t stream)
{
  const float* x     = (const float*)d_in[0];
  const float* Wqkv  = (const float*)d_in[1];
  const float* bqkv  = (const float*)d_in[2];
  const float* Wproj = (const float*)d_in[3];
  const float* bproj = (const float*)d_in[4];
  float* out = (float*)d_out;

  char* p = (char*)d_ws;
  bf16* Xb     = (bf16*)p;  p += (size_t)MM*CC*2;        // 8 MB (dead after QKV GEMM)
  bf16* WqkvT  = (bf16*)p;  p += (size_t)3*CC*CC*2;      // 6 MB
  bf16* WprojT = (bf16*)p;  p += (size_t)CC*CC*2;        // 2 MB
  bf16* Qb     = (bf16*)p;  p += (size_t)MM*CC*2;        // 8 MB (B,N,T,D)
  bf16* Kb     = (bf16*)p;  p += (size_t)MM*CC*2;        // 8 MB
  bf16* Vb     = (bf16*)p;  p += (size_t)MM*CC*2;        // 8 MB
  bf16* Attn   = (bf16*)p;  p += (size_t)MM*CC*2;        // 8 MB (B,T,C)
  bf16* VTb    = Xb;                                     // reuse Xb: (B,N,D,T)

  k_convert<<<(MM*CC/4 + 255)/256, 256, 0, stream>>>(x, Xb, MM*CC/4);
  k_transpose<<<dim3(3*CC/32, CC/32), dim3(32, 8), 0, stream>>>(Wqkv, WqkvT, CC, 3*CC);
  k_transpose<<<dim3(CC/32, CC/32), dim3(32, 8), 0, stream>>>(Wproj, WprojT, CC, CC);

  k_gemm<0><<<dim3(3*CC/128, MM/128), 256, 0, stream>>>(Xb, WqkvT, bqkv, nullptr, Qb, Kb, Vb, CC);
  k_vtrans<<<dim3(DHEAD/32, TT/32, BB*NHEAD), dim3(32, 8), 0, stream>>>(Vb, VTb);
  k_attn<<<1024, 256, 0, stream>>>(Qb, Kb, VTb, Attn);
  k_gemm<1><<<dim3(CC/128, MM/128), 256, 0, stream>>>(Attn, WprojT, bproj, out, nullptr, nullptr, nullptr, CC);
}

// Round 6
// 164.567 us; speedup vs baseline: 1.4068x; 1.0797x over previous
//
#include <hip/hip_runtime.h>
#include <hip/hip_bf16.h>

#define BB 2
#define TT 2048
#define CC 1024
#define NHEAD 16
#define DHEAD 64
#define MM (BB*TT)
#define KVB 64

using bf16 = __hip_bfloat16;
typedef __bf16 bf16x8 __attribute__((ext_vector_type(8)));
typedef __bf16 bf16x4 __attribute__((ext_vector_type(4)));
typedef float f32x4 __attribute__((ext_vector_type(4)));

static __device__ __forceinline__ bf16 f2b(float f) { return __float2bfloat16(f); }
static __device__ __forceinline__ float fast_exp2(float f) { return __builtin_amdgcn_exp2f(f); }

// async global -> LDS, 16B per lane (dest must be wave-uniform base + lane*16)
static __device__ __forceinline__ void gload16(const bf16* g, bf16* l) {
  __builtin_amdgcn_global_load_lds((__attribute__((address_space(1))) const void*)g,
                                   (__attribute__((address_space(3))) void*)l, 16, 0, 0);
}

// ---------------- fp32 -> bf16 linear convert (vectorized) ----------------
__global__ void k_convert(const float* __restrict__ in, bf16* __restrict__ out, int n4) {
  int i = blockIdx.x * blockDim.x + threadIdx.x;
  if (i >= n4) return;
  float4 v = reinterpret_cast<const float4*>(in)[i];
  bf16 o[4] = { f2b(v.x), f2b(v.y), f2b(v.z), f2b(v.w) };
  reinterpret_cast<uint2*>(out)[i] = *reinterpret_cast<uint2*>(o);
}

// ------------- fp32 (R x Cc) -> bf16 transposed (Cc x R) -------------
__global__ void k_transpose(const float* __restrict__ W, bf16* __restrict__ WT, int R, int Cc) {
  __shared__ float tile[32][33];
  int c0 = blockIdx.x * 32, r0 = blockIdx.y * 32;
  int tx = threadIdx.x, ty = threadIdx.y;   // 32 x 8
#pragma unroll
  for (int i = 0; i < 4; ++i)
    tile[ty + 8*i][tx] = W[(size_t)(r0 + ty + 8*i) * Cc + c0 + tx];
  __syncthreads();
#pragma unroll
  for (int i = 0; i < 4; ++i)
    WT[(size_t)(c0 + ty + 8*i) * R + r0 + tx] = f2b(tile[tx][ty + 8*i]);
}

// ------------- per-head V (T x D) -> V^T (D x T), bf16 -------------
__global__ void k_vtrans(const bf16* __restrict__ V, bf16* __restrict__ VT) {
  __shared__ bf16 tile[32][33];
  const int bn = blockIdx.z;
  const int d0 = blockIdx.x * 32, t0 = blockIdx.y * 32;
  const size_t base = (size_t)bn * TT * DHEAD;
  int tx = threadIdx.x, ty = threadIdx.y;   // 32 x 8
#pragma unroll
  for (int i = 0; i < 4; ++i)
    tile[ty + 8*i][tx] = V[base + (size_t)(t0 + ty + 8*i) * DHEAD + d0 + tx];
  __syncthreads();
#pragma unroll
  for (int i = 0; i < 4; ++i)
    VT[base + (size_t)(d0 + ty + 8*i) * TT + t0 + tx] = tile[tx][ty + 8*i];
}

// ---------------- 128x128 bf16 GEMM (m97 structure: global_load_lds, linear LDS) ----------------
template<int MODE>
__global__ __launch_bounds__(256)
void k_gemm(const bf16* __restrict__ A, const bf16* __restrict__ Bt,
            const float* __restrict__ bias, float* __restrict__ outF,
            bf16* __restrict__ Qb, bf16* __restrict__ Kb, bf16* __restrict__ Vb,
            int K)
{
  const int tid  = threadIdx.x;
  const int wave = tid >> 6, lane = tid & 63;
  const int l16 = lane & 15, l4 = lane >> 4;
  const int wr = wave >> 1, wc = wave & 1;
  const int m0 = blockIdx.y * 128, n0 = blockIdx.x * 128;

  __shared__ __align__(16) bf16 As[128*32];   // linear [row][32]
  __shared__ __align__(16) bf16 Bs[128*32];

  f32x4 acc[4][4];
#pragma unroll
  for (int m = 0; m < 4; ++m)
#pragma unroll
    for (int n = 0; n < 4; ++n) acc[m][n] = 0.f;

  const int sr = tid >> 2;            // 0..63
  const int sc = (tid & 3) * 8;       // 0,8,16,24

  for (int k0 = 0; k0 < K; k0 += 32) {
    __syncthreads();
#pragma unroll
    for (int i = 0; i < 2; ++i) {
      gload16(&A [(size_t)(m0 + i*64 + sr) * K + k0 + sc], &As[i*2048 + tid*8]);
      gload16(&Bt[(size_t)(n0 + i*64 + sr) * K + k0 + sc], &Bs[i*2048 + tid*8]);
    }
    __syncthreads();
    bf16x8 af[4], bfr[4];
#pragma unroll
    for (int m = 0; m < 4; ++m)
      af[m] = *reinterpret_cast<const bf16x8*>(&As[(wr*64 + m*16 + l16)*32 + l4*8]);
#pragma unroll
    for (int n = 0; n < 4; ++n)
      bfr[n] = *reinterpret_cast<const bf16x8*>(&Bs[(wc*64 + n*16 + l16)*32 + l4*8]);
#pragma unroll
    for (int m = 0; m < 4; ++m)
#pragma unroll
      for (int n = 0; n < 4; ++n)
        acc[m][n] = __builtin_amdgcn_mfma_f32_16x16x32_bf16(af[m], bfr[n], acc[m][n], 0, 0, 0);
  }

  if (MODE == 0) {
    const int which = n0 >> 10;
    bf16* __restrict__ dst = (which == 0) ? Qb : (which == 1) ? Kb : Vb;
    const float qsc = (which == 0) ? 0.125f * 1.4426950408889634f : 1.0f;
#pragma unroll
    for (int m = 0; m < 4; ++m)
#pragma unroll
      for (int n = 0; n < 4; ++n)
#pragma unroll
        for (int j = 0; j < 4; ++j) {
          int gr = m0 + wr*64 + m*16 + l4*4 + j;
          int gc = n0 + wc*64 + n*16 + l16;
          float val = (acc[m][n][j] + bias[gc]) * qsc;
          int c = gc & (CC-1), head = c >> 6, d = c & 63;
          int b = gr >> 11, t = gr & (TT-1);
          dst[(((size_t)b*NHEAD + head)*TT + t)*DHEAD + d] = f2b(val);
        }
  } else {
#pragma unroll
    for (int m = 0; m < 4; ++m)
#pragma unroll
      for (int n = 0; n < 4; ++n)
#pragma unroll
        for (int j = 0; j < 4; ++j) {
          int gr = m0 + wr*64 + m*16 + l4*4 + j;
          int gc = n0 + wc*64 + n*16 + l16;
          outF[(size_t)gr * CC + gc] = acc[m][n][j] + bias[gc];
        }
  }
}

// ---------------- flash attention v5 ----------------
// KVB=64, slim LDS (27.6KB -> 4+ blocks/CU); K/V staged in LDS with T14 reg-prefetch;
// swapped-QK in-register softmax, exp2 domain, defer-max; XCD-aware block swizzle.
__global__ __launch_bounds__(256, 4)
void k_attn(const bf16* __restrict__ Qg, const bf16* __restrict__ Kg,
            const bf16* __restrict__ VTg, bf16* __restrict__ Aout)
{
  const int tid  = threadIdx.x;
  const int wave = tid >> 6, lane = tid & 63;
  const int l16 = lane & 15, l4 = lane >> 4;

  // XCD-aware swizzle: 1024 blocks = 8 XCDs x 128; each XCD owns 4 heads
  const int flat = blockIdx.x;
  const int xcd = flat & 7, i6 = flat >> 3;
  const int bn = xcd*4 + (i6 >> 5);          // 0..31 (b*16+h)
  const int q0 = (i6 & 31) * 64;
  const int b = bn >> 4, h = bn & (NHEAD-1);

  __shared__ __align__(16) bf16 Ks[KVB][72];       // [kv][d]
  __shared__ __align__(16) bf16 Vt[DHEAD][72];     // [d][kv]
  __shared__ __align__(16) bf16 Pl[4][16][72];     // per-wave P[q][kv]

  const size_t hb = (size_t)bn * TT * DHEAD;
  const bf16* __restrict__ Kbase = Kg + hb;
  const bf16* __restrict__ Vbase = VTg + hb;

  bf16x8 qf[2];
#pragma unroll
  for (int kk = 0; kk < 2; ++kk)
    qf[kk] = *reinterpret_cast<const bf16x8*>(
        &Qg[hb + (size_t)(q0 + wave*16 + l16) * DHEAD + kk*32 + l4*8]);

  f32x4 o[4];
#pragma unroll
  for (int n = 0; n < 4; ++n) o[n] = 0.f;
  float mrun = -1e30f, lrun = 0.f;   // per-lane stats for q = l16 (replicated across l4)

  // staging geometry: thread covers 16 elems (2 x bf16x8)
  const int sr = tid >> 2;            // 0..63
  const int sc = (tid & 3) * 16;      // 0,16,32,48

  bf16x8 kreg[2], vreg[2];
#pragma unroll
  for (int i = 0; i < 2; ++i) {
    kreg[i] = *reinterpret_cast<const bf16x8*>(&Kbase[(size_t)sr * DHEAD + sc + 8*i]);
    vreg[i] = *reinterpret_cast<const bf16x8*>(&Vbase[(size_t)sr * TT + sc + 8*i]);
  }
#pragma unroll
  for (int i = 0; i < 2; ++i) {
    *reinterpret_cast<bf16x8*>(&Ks[sr][sc + 8*i]) = kreg[i];
    *reinterpret_cast<bf16x8*>(&Vt[sr][sc + 8*i]) = vreg[i];
  }

  for (int t0 = 0; t0 < TT; t0 += KVB) {
    __syncthreads();                      // tile t0 visible in LDS
    const bool more = (t0 + KVB < TT);
    if (more) {                           // T14: issue next-tile loads now, commit later
#pragma unroll
      for (int i = 0; i < 2; ++i) {
        kreg[i] = *reinterpret_cast<const bf16x8*>(
            &Kbase[(size_t)(t0 + KVB + sr) * DHEAD + sc + 8*i]);
        vreg[i] = *reinterpret_cast<const bf16x8*>(
            &Vbase[(size_t)sr * TT + t0 + KVB + sc + 8*i]);
      }
    }

    // S^T = K Q^T : lane holds S^T[kv = n*16 + l4*4 + j][q = l16]
    f32x4 s[4];
#pragma unroll
    for (int n = 0; n < 4; ++n) s[n] = 0.f;
    __builtin_amdgcn_s_setprio(1);
#pragma unroll
    for (int n = 0; n < 4; ++n) {
      bf16x8 kf0 = *reinterpret_cast<const bf16x8*>(&Ks[n*16 + l16][l4*8]);
      bf16x8 kf1 = *reinterpret_cast<const bf16x8*>(&Ks[n*16 + l16][32 + l4*8]);
      s[n] = __builtin_amdgcn_mfma_f32_16x16x32_bf16(kf0, qf[0], s[n], 0, 0, 0);
      s[n] = __builtin_amdgcn_mfma_f32_16x16x32_bf16(kf1, qf[1], s[n], 0, 0, 0);
    }
    __builtin_amdgcn_s_setprio(0);

    // --- online softmax (exp2 domain), defer-max THR=8 ---
    float pm = s[0][0];
#pragma unroll
    for (int n = 0; n < 4; ++n)
#pragma unroll
      for (int j = 0; j < 4; ++j) pm = fmaxf(pm, s[n][j]);
    pm = fmaxf(pm, __shfl_xor(pm, 16, 64));
    pm = fmaxf(pm, __shfl_xor(pm, 32, 64));

    if (!__all(pm <= mrun + 8.f)) {
      float mn = fmaxf(mrun, pm);
      float corr = fast_exp2(mrun - mn);
      mrun = mn;
      lrun *= corr;
      float cj[4];
#pragma unroll
      for (int j = 0; j < 4; ++j)
        cj[j] = __shfl(corr, ((lane >> 4) << 2) + j, 64);
#pragma unroll
      for (int n = 0; n < 4; ++n)
#pragma unroll
        for (int j = 0; j < 4; ++j) o[n][j] *= cj[j];
    }

    float psum = 0.f;
#pragma unroll
    for (int n = 0; n < 4; ++n) {
      bf16x4 pk;
#pragma unroll
      for (int j = 0; j < 4; ++j) {
        float pv = fast_exp2(s[n][j] - mrun);
        psum += pv;
        pk[j] = (__bf16)pv;
      }
      *reinterpret_cast<bf16x4*>(&Pl[wave][l16][n*16 + l4*4]) = pk;
    }
    psum += __shfl_xor(psum, 16, 64);
    psum += __shfl_xor(psum, 32, 64);
    lrun += psum;

    // O += P V : A = P[q][kv] (per-wave LDS), B = V^T[d][kv] (LDS)
    bf16x8 pf[2];
#pragma unroll
    for (int kk = 0; kk < 2; ++kk)
      pf[kk] = *reinterpret_cast<const bf16x8*>(&Pl[wave][l16][kk*32 + l4*8]);
    __builtin_amdgcn_s_setprio(1);
#pragma unroll
    for (int n = 0; n < 4; ++n)
#pragma unroll
      for (int kk = 0; kk < 2; ++kk) {
        bf16x8 vf = *reinterpret_cast<const bf16x8*>(&Vt[n*16 + l16][kk*32 + l4*8]);
        o[n] = __builtin_amdgcn_mfma_f32_16x16x32_bf16(pf[kk], vf, o[n], 0, 0, 0);
      }
    __builtin_amdgcn_s_setprio(0);

    __syncthreads();                      // all waves done reading Ks/Vt
    if (more) {
#pragma unroll
      for (int i = 0; i < 2; ++i) {
        *reinterpret_cast<bf16x8*>(&Ks[sr][sc + 8*i]) = kreg[i];
        *reinterpret_cast<bf16x8*>(&Vt[sr][sc + 8*i]) = vreg[i];
      }
    }
  }

  // epilogue
  float linv = 1.0f / lrun;
  float lj[4];
#pragma unroll
  for (int j = 0; j < 4; ++j)
    lj[j] = __shfl(linv, ((lane >> 4) << 2) + j, 64);
#pragma unroll
  for (int j = 0; j < 4; ++j) {
    int gt = q0 + wave*16 + l4*4 + j;
#pragma unroll
    for (int n = 0; n < 4; ++n)
      Aout[((size_t)(b*TT + gt))*CC + h*DHEAD + n*16 + l16] = f2b(o[n][j] * lj[j]);
  }
}

extern "C" void kernel_launch(void* const* d_in, const int* in_sizes, int n_in,
                              void* d_out, int out_size, void* d_ws, size_t ws_size,
                              hipStream_t stream)
{
  const float* x     = (const float*)d_in[0];
  const float* Wqkv  = (const float*)d_in[1];
  const float* bqkv  = (const float*)d_in[2];
  const float* Wproj = (const float*)d_in[3];
  const float* bproj = (const float*)d_in[4];
  float* out = (float*)d_out;

  char* p = (char*)d_ws;
  bf16* Xb     = (bf16*)p;  p += (size_t)MM*CC*2;        // 8 MB (dead after QKV GEMM)
  bf16* WqkvT  = (bf16*)p;  p += (size_t)3*CC*CC*2;      // 6 MB
  bf16* WprojT = (bf16*)p;  p += (size_t)CC*CC*2;        // 2 MB
  bf16* Qb     = (bf16*)p;  p += (size_t)MM*CC*2;        // 8 MB (B,N,T,D)
  bf16* Kb     = (bf16*)p;  p += (size_t)MM*CC*2;        // 8 MB
  bf16* Vb     = (bf16*)p;  p += (size_t)MM*CC*2;        // 8 MB
  bf16* Attn   = (bf16*)p;  p += (size_t)MM*CC*2;        // 8 MB (B,T,C)
  bf16* VTb    = Xb;                                     // reuse Xb: (B,N,D,T)

  k_convert<<<(MM*CC/4 + 255)/256, 256, 0, stream>>>(x, Xb, MM*CC/4);
  k_transpose<<<dim3(3*CC/32, CC/32), dim3(32, 8), 0, stream>>>(Wqkv, WqkvT, CC, 3*CC);
  k_transpose<<<dim3(CC/32, CC/32), dim3(32, 8), 0, stream>>>(Wproj, WprojT, CC, CC);

  k_gemm<0><<<dim3(3*CC/128, MM/128), 256, 0, stream>>>(Xb, WqkvT, bqkv, nullptr, Qb, Kb, Vb, CC);
  k_vtrans<<<dim3(DHEAD/32, TT/32, BB*NHEAD), dim3(32, 8), 0, stream>>>(Vb, VTb);
  k_attn<<<1024, 256, 0, stream>>>(Qb, Kb, VTb, Attn);
  k_gemm<1><<<dim3(CC/128, MM/128), 256, 0, stream>>>(Attn, WprojT, bproj, out, nullptr, nullptr, nullptr, CC);
}